// Round 4
// baseline (77.227 us; speedup 1.0000x reference)
//
#include <hip/hip_runtime.h>
#include <math.h>

typedef unsigned int uint;
typedef unsigned long long ull;

__device__ __forceinline__ float lrelu(float z){ return z > 0.f ? z : 0.5f*z; }
__device__ __forceinline__ float reluf(float z){ return fmaxf(z, 0.f); }
__device__ __forceinline__ float sigm(float z){ return 1.f/(1.f + __expf(-z)); }
__device__ __forceinline__ float tanh_fast(float z){ return 2.f/(1.f + __expf(-2.f*z)) - 1.f; }

// ============ K1: LSTM (blocks 0..7) + consts (block 8) ============
// consts layout: [0]=c1 [1]=c2 [2..9]=P[8] [10..17]=Q[8] [18]=pA [19]=qA [20]=pB [21]=qB
__global__ __launch_bounds__(256) void prep_kernel(
    const float* __restrict__ W1, const float* __restrict__ a1,
    const float* __restrict__ W2, const float* __restrict__ a2,
    float* __restrict__ consts,
    const float* __restrict__ ipop,
    const float* __restrict__ wih0, const float* __restrict__ whh0,
    const float* __restrict__ bih0, const float* __restrict__ bhh0,
    const float* __restrict__ wih1, const float* __restrict__ whh1,
    const float* __restrict__ bih1, const float* __restrict__ bhh1,
    float* __restrict__ ip_out)
{
  __shared__ float redA[256], redB[256];
  const int bid = blockIdx.x;
  const int t = threadIdx.x;

  if (bid < 8){
    // ---- LSTM: 8 blocks x 64 threads = 512 sequences ----
    if (t >= 64) return;
    const int b = bid*64 + t;
    float wi0[4], wh0[4], bb0[4], wi1[4], wh1[4], bb1[4];
    #pragma unroll
    for (int k = 0; k < 4; ++k){
      wi0[k]=wih0[k]; wh0[k]=whh0[k]; bb0[k]=bih0[k]+bhh0[k];
      wi1[k]=wih1[k]; wh1[k]=whh1[k]; bb1[k]=bih1[k]+bhh1[k];
    }
    float h1=0.f, c1v=0.f, h2=0.f, c2v=0.f;
    for (int tt = 0; tt < 64; ++tt){
      float x = ipop[b*64 + tt];
      float gi = sigm     (__fmaf_rn(x, wi0[0], __fmaf_rn(h1, wh0[0], bb0[0])));
      float gf = sigm     (__fmaf_rn(x, wi0[1], __fmaf_rn(h1, wh0[1], bb0[1])));
      float gg = tanh_fast(__fmaf_rn(x, wi0[2], __fmaf_rn(h1, wh0[2], bb0[2])));
      float go = sigm     (__fmaf_rn(x, wi0[3], __fmaf_rn(h1, wh0[3], bb0[3])));
      c1v = gf*c1v + gi*gg; h1 = go*tanh_fast(c1v);
      float hi2 = sigm     (__fmaf_rn(h1, wi1[0], __fmaf_rn(h2, wh1[0], bb1[0])));
      float hf2 = sigm     (__fmaf_rn(h1, wi1[1], __fmaf_rn(h2, wh1[1], bb1[1])));
      float hg2 = tanh_fast(__fmaf_rn(h1, wi1[2], __fmaf_rn(h2, wh1[2], bb1[2])));
      float ho2 = sigm     (__fmaf_rn(h1, wi1[3], __fmaf_rn(h2, wh1[3], bb1[3])));
      c2v = hf2*c2v + hi2*hg2; h2 = ho2*tanh_fast(c2v);
      ip_out[b*64 + tt] = h2;
    }
    return;
  }
  // ---- consts block ----
  {
    float s1 = 0.f, s2 = 0.f;
    for (int f = t; f < 512; f += 256){ float w = W1[f]; s1 += w*a1[f]; s2 += w*a1[512+f]; }
    redA[t] = s1; redB[t] = s2; __syncthreads();
    for (int st = 128; st > 0; st >>= 1){
      if (t < st){ redA[t] += redA[t+st]; redB[t] += redB[t+st]; }
      __syncthreads();
    }
    if (t == 0){ consts[0] = redA[0]; consts[1] = redB[0]; }
    __syncthreads();
    const int g = t >> 5, seg = t & 31;
    float accP = 0.f, accQ = 0.f;
    for (int k = 0; k < 16; ++k){
      int f = seg*16 + k;
      float w = W1[f];
      float v = w * W2[f*8 + g];
      if (w > 0.f) accP += v; else accQ += v;
    }
    redA[t] = accP; redB[t] = accQ; __syncthreads();
    for (int st = 16; st > 0; st >>= 1){
      if (seg < st){ redA[t] += redA[t+st]; redB[t] += redB[t+st]; }
      __syncthreads();
    }
    if (seg == 0){ consts[2+g] = redA[t]; consts[10+g] = redB[t]; }
    __syncthreads();
    if (t == 0){
      float pA=0.f,qA=0.f,pB=0.f,qB=0.f;
      for (int gg = 0; gg < 8; ++gg){
        pA += consts[2+gg]*a2[gg];   qA += consts[10+gg]*a2[gg];
        pB += consts[2+gg]*a2[8+gg]; qB += consts[10+gg]*a2[8+gg];
      }
      consts[18]=pA; consts[19]=qA; consts[20]=pB; consts[21]=qB;
    }
  }
}

// ============ K2: pack(ballot) + GAT1 + GAT2 + pooling + MHA + MLP head ============
// 512 threads/block, one batch per block.
__global__ __launch_bounds__(512) void gat_head_kernel(
    const int* __restrict__ adj, const float* __restrict__ feat,
    const float* __restrict__ timei,
    const float* __restrict__ Weight, const float* __restrict__ Wv,
    const float* __restrict__ consts, const float* __restrict__ ip,
    const float* __restrict__ mha_in_w, const float* __restrict__ mha_in_b,
    const float* __restrict__ mha_out_w, const float* __restrict__ mha_out_b,
    const float* __restrict__ fl1_w, const float* __restrict__ fl1_b,
    const float* __restrict__ fl2_w, const float* __restrict__ fl2_b,
    const float* __restrict__ fl3_w, const float* __restrict__ fl3_b,
    float* __restrict__ out)
{
  const int b = blockIdx.x, t = threadIdx.x;
  const int lane = t & 127;        // row/col index within the 128-node graph
  const int h    = t >> 7;         // 0..3: which 32-chunk of the other axis

  __shared__ ull   mku[256];                    // mku[i*2+w] bit q = adj[b][i][w*64+q] > 0
  __shared__ float xs[128], tim[128], uu[128], eA[128], eB[128], cs[128], cr[128], hm[128];
  __shared__ float red4[4][128];
  __shared__ float pool4[4][4][128];
  __shared__ float kv[192][2];
  __shared__ float hq[192], h2s[192], o2s[32];
  __shared__ float pden[2][192], pnum[2][192];
  __shared__ float pf[2][128];
  __shared__ float sred[8];

  const float c1 = consts[0], c2 = consts[1];
  const float pA = consts[18], qA = consts[19], pB = consts[20], qB = consts[21];

  // ---- phase 0: load features + coalesced ballot-pack of adjacency ----
  if (t < 128){ xs[t] = feat[b*128 + t]; tim[t] = timei[b*128 + t]; }
  {
    const int wv = t >> 6, ln = t & 63;
    const int* abase = adj + (((long)b) << 14) + wv*2048;
    #pragma unroll 8
    for (int it = 0; it < 32; ++it){
      int v = abase[it*64 + ln];
      ull m = __ballot(v > 0);
      if (ln == 0) mku[wv*32 + it] = m;
    }
  }
  __syncthreads();
  if (t < 64){
    float mx = fmaxf(xs[t], xs[t+64]);
    float mn = fminf(xs[t], xs[t+64]);
    #pragma unroll
    for (int off = 32; off; off >>= 1){
      mx = fmaxf(mx, __shfl_xor(mx, off));
      mn = fminf(mn, __shfl_xor(mn, off));
    }
    if (t == 0){ sred[0] = mx; sred[1] = mn; }
  }
  __syncthreads();
  const float maxE1 = (c1 >= 0.f) ? c1*sred[0] : c1*sred[1];

  // ---- GAT1 column pass: denominators ----
  {
    const int j = lane;
    const float ecol = c2*xs[j];
    const float cb = lrelu(maxE1 + ecol);        // exact shift (lrelu monotone)
    const int w = j >> 6, sh = j & 63;
    float sum = 0.f;
    const int i0 = h*32;
    #pragma unroll 8
    for (int k = 0; k < 32; ++k){
      int i = i0 + k;
      uint bit = (uint)((mku[i*2 + w] >> sh) & 1ull);
      float e = lrelu(__fmaf_rn(c1, xs[i], ecol));
      float v = __expf(e - cb);
      sum += bit ? v : 0.f;
    }
    red4[h][j] = sum;
    if (h == 0) cs[j] = cb;
  }
  __syncthreads();
  if (t < 128) cr[t] = 1.f/(red4[0][t] + red4[1][t] + red4[2][t] + red4[3][t]);
  __syncthreads();
  // ---- GAT1 row pass: u_i ----
  {
    const int i = lane;
    const float erow = c1*xs[i];
    ull bb = mku[i*2 + (h>>1)] >> ((h&1)*32);
    float s = 0.f;
    const int j0 = h*32;
    #pragma unroll 8
    for (int k = 0; k < 32; ++k){
      int j = j0 + k;
      float xj = xs[j];
      float e = lrelu(__fmaf_rn(c2, xj, erow));
      float att = __expf(e - cs[j]) * cr[j];
      s += ((bb>>k)&1ull) ? att*xj : 0.f;
    }
    red4[h][i] = s;
  }
  __syncthreads();
  if (t < 128){
    float u = red4[0][t] + red4[1][t] + red4[2][t] + red4[3][t];
    uu[t] = u;
    eA[t] = (u >= 0.f ? pA : qA)*u;
    eB[t] = (u >= 0.f ? pB : qB)*u;
  }
  __syncthreads();
  if (t < 64){
    float mx = fmaxf(eA[t], eA[t+64]);
    #pragma unroll
    for (int off = 32; off; off >>= 1) mx = fmaxf(mx, __shfl_xor(mx, off));
    if (t == 0) sred[2] = mx;
  }
  __syncthreads();
  const float eAmax = sred[2];

  // ---- GAT2 column pass ----
  {
    const int j = lane;
    const float ecol = eB[j];
    const float cb = lrelu(eAmax + ecol);
    const int w = j >> 6, sh = j & 63;
    float sum = 0.f;
    const int i0 = h*32;
    #pragma unroll 8
    for (int k = 0; k < 32; ++k){
      int i = i0 + k;
      uint bit = (uint)((mku[i*2 + w] >> sh) & 1ull);
      float e = lrelu(eA[i] + ecol);
      float v = __expf(e - cb);
      sum += bit ? v : 0.f;
    }
    red4[h][j] = sum;
    if (h == 0) cs[j] = cb;
  }
  __syncthreads();
  if (t < 128) cr[t] = 1.f/(red4[0][t] + red4[1][t] + red4[2][t] + red4[3][t]);
  __syncthreads();
  // ---- GAT2 row pass: sp, sn ----
  {
    const int i = lane;
    const float erow = eA[i];
    ull bb = mku[i*2 + (h>>1)] >> ((h&1)*32);
    float sp = 0.f, sn = 0.f;
    const int j0 = h*32;
    #pragma unroll 8
    for (int k = 0; k < 32; ++k){
      int j = j0 + k;
      float uj = uu[j];
      float e = lrelu(erow + eB[j]);
      float att = __expf(e - cs[j]) * cr[j];
      att = ((bb>>k)&1ull) ? att : 0.f;
      sp = __fmaf_rn(att, fmaxf(uj, 0.f), sp);
      sn = __fmaf_rn(att, fminf(uj, 0.f), sn);
    }
    pool4[0][h][i] = sp; pool4[1][h][i] = sn;
  }
  __syncthreads();
  if (t < 128){
    float sp = pool4[0][0][t] + pool4[0][1][t] + pool4[0][2][t] + pool4[0][3][t];
    float sn = pool4[1][0][t] + pool4[1][1][t] + pool4[1][2][t] + pool4[1][3][t];
    float acc = 0.f;
    #pragma unroll
    for (int g = 0; g < 8; ++g) acc += reluf(__fmaf_rn(sp, consts[2+g], sn*consts[10+g]));
    hm[t] = 0.125f*acc;
  }
  __syncthreads();

  // ---- attention pooling ----
  {
    const int n = lane;
    float a0=0.f, a1v=0.f, v0=0.f, v1=0.f;
    const int m0 = h*32;
    #pragma unroll 4
    for (int k = 0; k < 32; ++k){
      int m = m0 + k;
      float hmv = hm[m], tv = tim[m];
      float wg = Weight[(m<<7) + n], wvv = Wv[(m<<7) + n];
      a0 = __fmaf_rn(hmv, wg, a0); a1v = __fmaf_rn(tv, wg, a1v);
      v0 = __fmaf_rn(hmv, wvv, v0); v1 = __fmaf_rn(tv, wvv, v1);
    }
    pool4[0][h][n]=a0; pool4[1][h][n]=a1v; pool4[2][h][n]=v0; pool4[3][h][n]=v1;
  }
  if (t >= 256 && t < 320) hq[128 + (t-256)] = ip[b*64 + (t-256)];
  __syncthreads();
  if (t < 128){
    cs[t] = pool4[0][0][t] + pool4[0][1][t] + pool4[0][2][t] + pool4[0][3][t];  // A0
    cr[t] = pool4[1][0][t] + pool4[1][1][t] + pool4[1][2][t] + pool4[1][3][t];  // A1
    eA[t] = pool4[2][0][t] + pool4[2][1][t] + pool4[2][2][t] + pool4[2][3][t];  // V0
    eB[t] = pool4[3][0][t] + pool4[3][1][t] + pool4[3][2][t] + pool4[3][3][t];  // V1
  }
  __syncthreads();
  if (t < 128){
    float a0 = cs[t], a1v = cr[t];
    float mx = fmaxf(a0, a1v);
    float e0 = __expf(a0 - mx), e1 = __expf(a1v - mx);
    float rs = 1.f/(e0 + e1);
    float r0, r1;
    if (t < 64){ r0 = eA[2*t];     r1 = eA[2*t+1];   }
    else       { r0 = eB[2*t-128]; r1 = eB[2*t-127]; }
    hq[t] = (reluf(r0)*e0 + reluf(r1)*e1)*rs;
  }
  __syncthreads();

  // ---- MHA (dim-1) + residual ----
  const float wq = mha_in_w[0], wk = mha_in_w[1], wv = mha_in_w[2];
  const float bq = mha_in_b[0], bk = mha_in_b[1], bv = mha_in_b[2];
  const float wo = mha_out_w[0], bo = mha_out_b[0];
  if (t < 192){
    float hv_ = hq[t];
    kv[t][0] = __fmaf_rn(hv_, wk, bk);
    kv[t][1] = __fmaf_rn(hv_, wv, bv);
  }
  __syncthreads();
  if (t < 64){
    float k0 = kv[t][0], k1 = kv[t+64][0], k2 = kv[t+128][0];
    float mx = fmaxf(fmaxf(k0, k1), k2);
    float mn = fminf(fminf(k0, k1), k2);
    #pragma unroll
    for (int off = 32; off; off >>= 1){
      mx = fmaxf(mx, __shfl_xor(mx, off));
      mn = fminf(mn, __shfl_xor(mn, off));
    }
    if (t == 0){ sred[3] = mx; sred[4] = mn; }
  }
  __syncthreads();
  if (t < 384){
    const int half = (t >= 192), tt = t - half*192;
    float qi = __fmaf_rn(hq[tt], wq, bq);
    float mx = (qi >= 0.f) ? qi*sred[3] : qi*sred[4];
    float den = 0.f, num = 0.f;
    const int j0 = half*96;
    #pragma unroll 8
    for (int jj = 0; jj < 96; ++jj){
      int j = j0 + jj;
      float e = __expf(__fmaf_rn(qi, kv[j][0], -mx));
      den += e; num = __fmaf_rn(e, kv[j][1], num);
    }
    pden[half][tt] = den; pnum[half][tt] = num;
  }
  __syncthreads();
  if (t < 192){
    float den = pden[0][t] + pden[1][t];
    float num = pnum[0][t] + pnum[1][t];
    h2s[t] = __fmaf_rn(num/den, wo, bo) + hq[t];
  }
  __syncthreads();
  // ---- fl1: 192 -> 128, relu (2-way split) ----
  if (t < 256){
    const int n = t & 127, half = t >> 7;
    float acc = 0.f;
    const int i0 = half*96;
    #pragma unroll 8
    for (int k = 0; k < 96; ++k){
      int i = i0 + k;
      acc = __fmaf_rn(h2s[i], fl1_w[i*128 + n], acc);
    }
    pf[half][n] = acc;
  }
  __syncthreads();
  if (t < 128) red4[0][t] = reluf(pf[0][t] + pf[1][t] + fl1_b[t]);
  __syncthreads();
  // ---- fl2: 128 -> 32, tanh (4-way split) ----
  if (t < 128){
    const int n = t & 31, seg = t >> 5;
    float p = 0.f;
    #pragma unroll 8
    for (int k = 0; k < 32; ++k){
      int i = seg*32 + k;
      p = __fmaf_rn(red4[0][i], fl2_w[i*32 + n], p);
    }
    red4[1][t] = p;
  }
  __syncthreads();
  if (t < 32){
    float s = red4[1][t] + red4[1][t+32] + red4[1][t+64] + red4[1][t+96] + fl2_b[t];
    o2s[t] = tanh_fast(s);
  }
  __syncthreads();
  // ---- fl3: 32 -> 1, relu ----
  if (t < 64){
    float p = (t < 32) ? o2s[t]*fl3_w[t] : 0.f;
    #pragma unroll
    for (int off = 32; off; off >>= 1) p += __shfl_xor(p, off);
    if (t == 0) out[b] = reluf(p + fl3_b[0]);
  }
}

extern "C" void kernel_launch(void* const* d_in, const int* in_sizes, int n_in,
                              void* d_out, int out_size, void* d_ws, size_t ws_size,
                              hipStream_t stream) {
  const int*   adj    = (const int*)  d_in[0];
  const float* feat   = (const float*)d_in[1];
  const float* timei  = (const float*)d_in[2];
  const float* ipop   = (const float*)d_in[3];
  const float* W1     = (const float*)d_in[4];
  const float* a1     = (const float*)d_in[5];
  const float* W2     = (const float*)d_in[6];
  const float* a2     = (const float*)d_in[7];
  const float* Weight = (const float*)d_in[8];
  const float* Wv     = (const float*)d_in[9];
  const float* wih0   = (const float*)d_in[10];
  const float* whh0   = (const float*)d_in[11];
  const float* bih0   = (const float*)d_in[12];
  const float* bhh0   = (const float*)d_in[13];
  const float* wih1   = (const float*)d_in[14];
  const float* whh1   = (const float*)d_in[15];
  const float* bih1   = (const float*)d_in[16];
  const float* bhh1   = (const float*)d_in[17];
  const float* mha_in_w  = (const float*)d_in[18];
  const float* mha_in_b  = (const float*)d_in[19];
  const float* mha_out_w = (const float*)d_in[20];
  const float* mha_out_b = (const float*)d_in[21];
  const float* fl1_w = (const float*)d_in[22];
  const float* fl1_b = (const float*)d_in[23];
  const float* fl2_w = (const float*)d_in[24];
  const float* fl2_b = (const float*)d_in[25];
  const float* fl3_w = (const float*)d_in[26];
  const float* fl3_b = (const float*)d_in[27];

  float* consts = (float*)d_ws;                 // 32 floats
  float* ip     = (float*)d_ws + 32;            // 512*64 floats

  prep_kernel<<<9, 256, 0, stream>>>(W1, a1, W2, a2, consts,
                                     ipop, wih0, whh0, bih0, bhh0,
                                     wih1, whh1, bih1, bhh1, ip);
  gat_head_kernel<<<512, 512, 0, stream>>>(adj, feat, timei, Weight, Wv, consts, ip,
                                           mha_in_w, mha_in_b, mha_out_w, mha_out_b,
                                           fl1_w, fl1_b, fl2_w, fl2_b, fl3_w, fl3_b,
                                           (float*)d_out);
}

// Round 5
// 72.357 us; speedup vs baseline: 1.0673x; 1.0673x over previous
//
#include <hip/hip_runtime.h>
#include <math.h>

typedef unsigned int uint;
typedef unsigned long long ull;

__device__ __forceinline__ float lrelu(float z){ return fmaxf(z, 0.5f*z); }
__device__ __forceinline__ float reluf(float z){ return fmaxf(z, 0.f); }
__device__ __forceinline__ float sigm(float z){ return 1.f/(1.f + __expf(-z)); }
__device__ __forceinline__ float tanh_fast(float z){ return 2.f/(1.f + __expf(-2.f*z)) - 1.f; }

// ================= K1: pack (0..511) + LSTM (512..519) + consts (520) =================
// gpk [b][i][h] (ull): bit k = adj[b][i][64h+k] > 0        (row-major)
// gpkT[b][j][h] (ull): bit k = adj[b][64h+k][j] > 0        (col-major)
// consts: [0]=c1 [1]=c2 [2..9]=P [10..17]=Q [18]=pA [19]=qA [20]=pB [21]=qB
__global__ __launch_bounds__(256) void pack_prep_kernel(
    const int* __restrict__ adj, ull* __restrict__ gpk, ull* __restrict__ gpkT,
    const float* __restrict__ W1, const float* __restrict__ a1,
    const float* __restrict__ W2, const float* __restrict__ a2,
    float* __restrict__ consts,
    const float* __restrict__ ipop,
    const float* __restrict__ wih0, const float* __restrict__ whh0,
    const float* __restrict__ bih0, const float* __restrict__ bhh0,
    const float* __restrict__ wih1, const float* __restrict__ whh1,
    const float* __restrict__ bih1, const float* __restrict__ bhh1,
    float* __restrict__ ip_out)
{
  const int bid = blockIdx.x, t = threadIdx.x;

  if (bid < 512){
    __shared__ ull rowW[256];      // rowW[i*2+ch] bit k = adj[i][ch*64+k]
    const int wv = t >> 6, ln = t & 63;
    const int* abase = adj + (((long)bid) << 14) + wv*4096;
    #pragma unroll 8
    for (int it = 0; it < 64; ++it){           // row = 32wv + it>>1, colhalf = it&1
      int v = abase[it*64 + ln];               // wave-contiguous 256B load
      ull m = __ballot(v > 0);
      if (ln == 0) rowW[wv*64 + it] = m;       // == (32wv + it>>1)*2 + (it&1)
    }
    __syncthreads();
    // transpose: thread (j=t&127, w2=t>>7) builds colword bits k = row 64*w2+k
    const int j = t & 127, w2 = t >> 7;
    const int wsel = j >> 6, bsel = j & 63;
    ull outw = 0;
    #pragma unroll 8
    for (int k = 0; k < 64; ++k){
      int i = w2*64 + k;
      ull bit = (rowW[i*2 + wsel] >> bsel) & 1ull;   // broadcast ds_read
      outw |= bit << k;
    }
    gpkT[bid*256 + j*2 + w2] = outw;
    gpk [bid*256 + t] = rowW[t];
    return;
  }
  if (bid < 520){
    // ---- LSTM: 8 blocks x 64 threads = 512 sequences ----
    if (t >= 64) return;
    const int b = (bid - 512)*64 + t;
    float wi0[4], wh0[4], bb0[4], wi1[4], wh1[4], bb1[4];
    #pragma unroll
    for (int k = 0; k < 4; ++k){
      wi0[k]=wih0[k]; wh0[k]=whh0[k]; bb0[k]=bih0[k]+bhh0[k];
      wi1[k]=wih1[k]; wh1[k]=whh1[k]; bb1[k]=bih1[k]+bhh1[k];
    }
    float h1=0.f, c1v=0.f, h2=0.f, c2v=0.f;
    for (int tt = 0; tt < 64; ++tt){
      float x = ipop[b*64 + tt];
      float gi = sigm     (__fmaf_rn(x, wi0[0], __fmaf_rn(h1, wh0[0], bb0[0])));
      float gf = sigm     (__fmaf_rn(x, wi0[1], __fmaf_rn(h1, wh0[1], bb0[1])));
      float gg = tanh_fast(__fmaf_rn(x, wi0[2], __fmaf_rn(h1, wh0[2], bb0[2])));
      float go = sigm     (__fmaf_rn(x, wi0[3], __fmaf_rn(h1, wh0[3], bb0[3])));
      c1v = gf*c1v + gi*gg; h1 = go*tanh_fast(c1v);
      float hi2 = sigm     (__fmaf_rn(h1, wi1[0], __fmaf_rn(h2, wh1[0], bb1[0])));
      float hf2 = sigm     (__fmaf_rn(h1, wi1[1], __fmaf_rn(h2, wh1[1], bb1[1])));
      float hg2 = tanh_fast(__fmaf_rn(h1, wi1[2], __fmaf_rn(h2, wh1[2], bb1[2])));
      float ho2 = sigm     (__fmaf_rn(h1, wi1[3], __fmaf_rn(h2, wh1[3], bb1[3])));
      c2v = hf2*c2v + hi2*hg2; h2 = ho2*tanh_fast(c2v);
      ip_out[b*64 + tt] = h2;
    }
    return;
  }
  // ---- consts block ----
  {
    __shared__ float redA[256], redB[256];
    float s1 = 0.f, s2 = 0.f;
    for (int f = t; f < 512; f += 256){ float w = W1[f]; s1 += w*a1[f]; s2 += w*a1[512+f]; }
    redA[t] = s1; redB[t] = s2; __syncthreads();
    for (int st = 128; st > 0; st >>= 1){
      if (t < st){ redA[t] += redA[t+st]; redB[t] += redB[t+st]; }
      __syncthreads();
    }
    if (t == 0){ consts[0] = redA[0]; consts[1] = redB[0]; }
    __syncthreads();
    const int g = t >> 5, seg = t & 31;
    float accP = 0.f, accQ = 0.f;
    for (int k = 0; k < 16; ++k){
      int f = seg*16 + k;
      float w = W1[f];
      float v = w * W2[f*8 + g];
      if (w > 0.f) accP += v; else accQ += v;
    }
    redA[t] = accP; redB[t] = accQ; __syncthreads();
    for (int st = 16; st > 0; st >>= 1){
      if (seg < st){ redA[t] += redA[t+st]; redB[t] += redB[t+st]; }
      __syncthreads();
    }
    if (seg == 0){ consts[2+g] = redA[t]; consts[10+g] = redB[t]; }
    __syncthreads();
    if (t == 0){
      float pA=0.f,qA=0.f,pB=0.f,qB=0.f;
      for (int gg = 0; gg < 8; ++gg){
        pA += consts[2+gg]*a2[gg];   qA += consts[10+gg]*a2[gg];
        pB += consts[2+gg]*a2[8+gg]; qB += consts[10+gg]*a2[8+gg];
      }
      consts[18]=pA; consts[19]=qA; consts[20]=pB; consts[21]=qB;
    }
  }
}

// ================= K2: exp-factorized GAT1+GAT2 + pooling + MHA + MLP head =================
// 256 threads, one batch per block. Inner pass loops have NO exp and NO mask LDS reads.
__global__ __launch_bounds__(256) void gat_head_kernel(
    const ull* __restrict__ gpk, const ull* __restrict__ gpkT,
    const float* __restrict__ feat, const float* __restrict__ timei,
    const float* __restrict__ Weight, const float* __restrict__ Wv,
    const float* __restrict__ consts, const float* __restrict__ ip,
    const float* __restrict__ mha_in_w, const float* __restrict__ mha_in_b,
    const float* __restrict__ mha_out_w, const float* __restrict__ mha_out_b,
    const float* __restrict__ fl1_w, const float* __restrict__ fl1_b,
    const float* __restrict__ fl2_w, const float* __restrict__ fl2_b,
    const float* __restrict__ fl3_w, const float* __restrict__ fl3_b,
    float* __restrict__ out)
{
  const int b = blockIdx.x, t = threadIdx.x;
  const int lane = t & 127, h = t >> 7;        // h in {0,1}: 64-chunk of the other axis

  __shared__ float  xs[128], tim[128], hm[128], eAs[128], thr1[128];
  __shared__ float2 f2a[128];                  // {E1_i, Eh_i}
  __shared__ float2 red2[2][128];              // pass partials / V-pair staging / fl1 partials
  __shared__ float4 q4[128];                   // {G1,G2,thr,-} then {Gp1,Gp2,Gn1,Gn2}
  __shared__ float4 pool4[2][128];             // row2 partials / pooling partials
  __shared__ float2 kv[192];
  __shared__ float  hq[192], h2s[192];
  __shared__ float  sred[8];

  const float c1 = consts[0], c2 = consts[1];
  const float pA = consts[18], qA = consts[19], pB = consts[20], qB = consts[21];

  // ---- phase 0: loads (masks into registers) ----
  float ipreg = 0.f;
  if (t < 128){ xs[t] = feat[b*128 + t]; tim[t] = timei[b*128 + t]; }
  if (t >= 192) ipreg = ip[b*64 + (t - 192)];
  const ull rowm = gpk [b*256 + lane*2 + h];   // bit k = adj[lane][64h+k]
  const ull colm = gpkT[b*256 + lane*2 + h];   // bit k = adj[64h+k][lane]
  __syncthreads();
  if (t < 64){
    float mx = fmaxf(xs[t], xs[t+64]);
    float mn = fminf(xs[t], xs[t+64]);
    #pragma unroll
    for (int off = 32; off; off >>= 1){
      mx = fmaxf(mx, __shfl_xor(mx, off));
      mn = fminf(mn, __shfl_xor(mn, off));
    }
    if (t == 0){ sred[0] = mx; sred[1] = mn; }
  }
  __syncthreads();

  // ---- phase 0b: per-node factors for GAT1 ----
  float myE1=0.f, myEh=0.f, myA=0.f, myB=0.f, mythr=0.f, myx=0.f;
  {
    const float rmax = (c1 >= 0.f) ? c1*sred[0] : c1*sred[1];
    if (t < 128){
      myx = xs[t];
      float r  = c1*myx;
      float cj = c2*myx;
      float cb = lrelu(rmax + cj);
      myE1  = __expf(r - rmax);
      myEh  = __expf(0.5f*(r - rmax));
      myA   = __expf(rmax + cj - cb);
      myB   = __expf(0.5f*(rmax + cj) - cb);
      mythr = __expf(-cj - rmax);
      f2a[t] = make_float2(myE1, myEh);
      thr1[t] = mythr;
    }
  }
  __syncthreads();

  // ---- GAT1 col pass: S1,S2 per column ----
  {
    const float thrj = thr1[lane];
    float s1 = 0.f, s2 = 0.f;
    #pragma unroll 8
    for (int k = 0; k < 64; ++k){
      float2 E = f2a[64*h + k];                // broadcast
      bool m = ((colm >> k) & 1ull);
      bool cond = (E.x >= thrj);
      s1 += (m &&  cond) ? E.x : 0.f;
      s2 += (m && !cond) ? E.y : 0.f;
    }
    red2[h][lane] = make_float2(s1, s2);
  }
  __syncthreads();
  // ---- combine: cr, per-column G table ----
  if (t < 128){
    float2 a = red2[0][t], bb = red2[1][t];
    float den = __fmaf_rn(myA, a.x + bb.x, myB*(a.y + bb.y));
    float cr = 1.f/den;
    q4[t] = make_float4(myA*cr*myx, myB*cr*myx, mythr, 0.f);
  }
  __syncthreads();
  // ---- GAT1 row pass: u_i = E1_i*T1 + Eh_i*T2 ----
  {
    const float2 Eo = f2a[lane];
    float t1 = 0.f, t2 = 0.f;
    #pragma unroll 8
    for (int k = 0; k < 64; ++k){
      float4 G = q4[64*h + k];                 // broadcast
      bool m = ((rowm >> k) & 1ull);
      bool cond = (Eo.x >= G.z);
      t1 += (m &&  cond) ? G.x : 0.f;
      t2 += (m && !cond) ? G.y : 0.f;
    }
    red2[h][lane] = make_float2(t1, t2);
  }
  __syncthreads();
  // ---- u, eA, eB; eA max ----
  float u = 0.f, eBv = 0.f, eAv = 0.f;
  if (t < 128){
    float2 a = red2[0][t], bb = red2[1][t];
    u = __fmaf_rn(myE1, a.x + bb.x, myEh*(a.y + bb.y));
    eAv = (u >= 0.f ? pA : qA)*u;
    eBv = (u >= 0.f ? pB : qB)*u;
    eAs[t] = eAv;
  }
  __syncthreads();
  if (t < 64){
    float mx = fmaxf(eAs[t], eAs[t+64]);
    #pragma unroll
    for (int off = 32; off; off >>= 1) mx = fmaxf(mx, __shfl_xor(mx, off));
    if (t == 0) sred[2] = mx;
  }
  __syncthreads();
  // ---- per-node factors for GAT2 ----
  float myE1b=0.f, myEhb=0.f, myA2=0.f, myB2=0.f;
  {
    const float eAmax = sred[2];
    if (t < 128){
      float cb = lrelu(eAmax + eBv);
      myE1b = __expf(eAv - eAmax);
      myEhb = __expf(0.5f*(eAv - eAmax));
      myA2  = __expf(eAmax + eBv - cb);
      myB2  = __expf(0.5f*(eAmax + eBv) - cb);
      float th = __expf(-eBv - eAmax);
      f2a[t] = make_float2(myE1b, myEhb);
      thr1[t] = th;
    }
  }
  __syncthreads();
  // ---- GAT2 col pass ----
  {
    const float thrj = thr1[lane];
    float s1 = 0.f, s2 = 0.f;
    #pragma unroll 8
    for (int k = 0; k < 64; ++k){
      float2 E = f2a[64*h + k];
      bool m = ((colm >> k) & 1ull);
      bool cond = (E.x >= thrj);
      s1 += (m &&  cond) ? E.x : 0.f;
      s2 += (m && !cond) ? E.y : 0.f;
    }
    red2[h][lane] = make_float2(s1, s2);
  }
  __syncthreads();
  if (t < 128){
    float2 a = red2[0][t], bb = red2[1][t];
    float den = __fmaf_rn(myA2, a.x + bb.x, myB2*(a.y + bb.y));
    float cr = 1.f/den;
    float up = fmaxf(u, 0.f), un = fminf(u, 0.f);
    q4[t] = make_float4(myA2*cr*up, myB2*cr*up, myA2*cr*un, myB2*cr*un);
  }
  __syncthreads();
  // ---- GAT2 row pass: sp/sn (4 accumulators) ----
  {
    const float2 Eo = f2a[lane];
    float sp1=0.f, sp2=0.f, sn1=0.f, sn2=0.f;
    #pragma unroll 8
    for (int k = 0; k < 64; ++k){
      int j = 64*h + k;
      float4 G = q4[j];
      float thj = thr1[j];
      bool m = ((rowm >> k) & 1ull);
      bool cond = (Eo.x >= thj);
      sp1 += (m &&  cond) ? G.x : 0.f;
      sp2 += (m && !cond) ? G.y : 0.f;
      sn1 += (m &&  cond) ? G.z : 0.f;
      sn2 += (m && !cond) ? G.w : 0.f;
    }
    pool4[h][lane] = make_float4(sp1, sp2, sn1, sn2);
  }
  __syncthreads();
  if (t < 128){
    float4 a = pool4[0][t], bb = pool4[1][t];
    float sp = __fmaf_rn(myE1b, a.x + bb.x, myEhb*(a.y + bb.y));
    float sn = __fmaf_rn(myE1b, a.z + bb.z, myEhb*(a.w + bb.w));
    float acc = 0.f;
    #pragma unroll
    for (int g = 0; g < 8; ++g) acc += reluf(__fmaf_rn(sp, consts[2+g], sn*consts[10+g]));
    hm[t] = 0.125f*acc;
  }
  __syncthreads();

  // ---- attention pooling over Weight/Wv (global, L2-resident) ----
  {
    const int n = lane;
    float a0=0.f, a1v=0.f, v0=0.f, v1=0.f;
    const int m0 = h*64;
    #pragma unroll 4
    for (int k = 0; k < 64; ++k){
      int m = m0 + k;
      float hmv = hm[m], tv = tim[m];
      float wg = Weight[(m<<7) + n], wvv = Wv[(m<<7) + n];
      a0 = __fmaf_rn(hmv, wg, a0); a1v = __fmaf_rn(tv, wg, a1v);
      v0 = __fmaf_rn(hmv, wvv, v0); v1 = __fmaf_rn(tv, wvv, v1);
    }
    pool4[h][n] = make_float4(a0, a1v, v0, v1);
  }
  __syncthreads();
  float att0 = 0.f, att1 = 0.f, rsv = 0.f;
  if (t < 128){
    float4 a = pool4[0][t], bb = pool4[1][t];
    float A0 = a.x + bb.x, A1 = a.y + bb.y;
    red2[0][t] = make_float2(a.z + bb.z, a.w + bb.w);   // {V0, V1}
    float mx = fmaxf(A0, A1);
    att0 = __expf(A0 - mx); att1 = __expf(A1 - mx);
    rsv = 1.f/(att0 + att1);
  }
  __syncthreads();
  if (t < 128){
    float r0, r1;
    if (t < 64){ r0 = red2[0][2*t].x;     r1 = red2[0][2*t+1].x; }
    else       { r0 = red2[0][2*t-128].y; r1 = red2[0][2*t-127].y; }
    hq[t] = (reluf(r0)*att0 + reluf(r1)*att1)*rsv;
  }
  if (t >= 192) hq[128 + (t - 192)] = ipreg;
  __syncthreads();

  // ---- MHA (dim-1) + residual ----
  const float wq = mha_in_w[0], wk = mha_in_w[1], wv = mha_in_w[2];
  const float bq = mha_in_b[0], bk = mha_in_b[1], bv = mha_in_b[2];
  const float wo = mha_out_w[0], bo = mha_out_b[0];
  if (t < 192){
    float hv_ = hq[t];
    kv[t] = make_float2(__fmaf_rn(hv_, wk, bk), __fmaf_rn(hv_, wv, bv));
  }
  __syncthreads();
  if (t < 64){
    float k0 = kv[t].x, k1 = kv[t+64].x, k2 = kv[t+128].x;
    float mx = fmaxf(fmaxf(k0, k1), k2);
    float mn = fminf(fminf(k0, k1), k2);
    #pragma unroll
    for (int off = 32; off; off >>= 1){
      mx = fmaxf(mx, __shfl_xor(mx, off));
      mn = fminf(mn, __shfl_xor(mn, off));
    }
    if (t == 0){ sred[3] = mx; sred[4] = mn; }
  }
  __syncthreads();
  if (t < 192){
    float hv_ = hq[t];
    float qi = __fmaf_rn(hv_, wq, bq);
    float mx = (qi >= 0.f) ? qi*sred[3] : qi*sred[4];
    float den = 0.f, num = 0.f;
    #pragma unroll 8
    for (int j = 0; j < 192; ++j){
      float2 K = kv[j];
      float e = __expf(__fmaf_rn(qi, K.x, -mx));
      den += e; num = __fmaf_rn(e, K.y, num);
    }
    h2s[t] = __fmaf_rn(num/den, wo, bo) + hv_;
  }
  __syncthreads();
  // ---- fl1: 192 -> 128, relu (2-way split over j) ----
  {
    const int n = t & 127;
    float acc = 0.f;
    const int i0 = h*96;
    #pragma unroll 8
    for (int k = 0; k < 96; ++k){
      int i = i0 + k;
      acc = __fmaf_rn(h2s[i], fl1_w[i*128 + n], acc);
    }
    red2[h][n].x = acc;
  }
  __syncthreads();
  if (t < 128) thr1[t] = reluf(red2[0][t].x + red2[1][t].x + fl1_b[t]);
  __syncthreads();
  // ---- fl2: 128 -> 32, tanh (4-way split) ----
  if (t < 128){
    const int n = t & 31, seg = t >> 5;
    float p = 0.f;
    #pragma unroll 8
    for (int k = 0; k < 32; ++k){
      int i = seg*32 + k;
      p = __fmaf_rn(thr1[i], fl2_w[i*32 + n], p);
    }
    eAs[t] = p;
  }
  __syncthreads();
  if (t < 32) hm[t] = tanh_fast(eAs[t] + eAs[t+32] + eAs[t+64] + eAs[t+96] + fl2_b[t]);
  __syncthreads();
  // ---- fl3: 32 -> 1, relu ----
  if (t < 64){
    float p = (t < 32) ? hm[t]*fl3_w[t] : 0.f;
    #pragma unroll
    for (int off = 32; off; off >>= 1) p += __shfl_xor(p, off);
    if (t == 0) out[b] = reluf(p + fl3_b[0]);
  }
}

extern "C" void kernel_launch(void* const* d_in, const int* in_sizes, int n_in,
                              void* d_out, int out_size, void* d_ws, size_t ws_size,
                              hipStream_t stream) {
  const int*   adj    = (const int*)  d_in[0];
  const float* feat   = (const float*)d_in[1];
  const float* timei  = (const float*)d_in[2];
  const float* ipop   = (const float*)d_in[3];
  const float* W1     = (const float*)d_in[4];
  const float* a1     = (const float*)d_in[5];
  const float* W2     = (const float*)d_in[6];
  const float* a2     = (const float*)d_in[7];
  const float* Weight = (const float*)d_in[8];
  const float* Wv     = (const float*)d_in[9];
  const float* wih0   = (const float*)d_in[10];
  const float* whh0   = (const float*)d_in[11];
  const float* bih0   = (const float*)d_in[12];
  const float* bhh0   = (const float*)d_in[13];
  const float* wih1   = (const float*)d_in[14];
  const float* whh1   = (const float*)d_in[15];
  const float* bih1   = (const float*)d_in[16];
  const float* bhh1   = (const float*)d_in[17];
  const float* mha_in_w  = (const float*)d_in[18];
  const float* mha_in_b  = (const float*)d_in[19];
  const float* mha_out_w = (const float*)d_in[20];
  const float* mha_out_b = (const float*)d_in[21];
  const float* fl1_w = (const float*)d_in[22];
  const float* fl1_b = (const float*)d_in[23];
  const float* fl2_w = (const float*)d_in[24];
  const float* fl2_b = (const float*)d_in[25];
  const float* fl3_w = (const float*)d_in[26];
  const float* fl3_b = (const float*)d_in[27];

  ull*   gpk    = (ull*)d_ws;                 // 512*256 ull = 1 MB
  ull*   gpkT   = gpk + 131072;               // 1 MB
  float* consts = (float*)(gpkT + 131072);    // 32 floats
  float* ip     = consts + 32;                // 512*64 floats

  pack_prep_kernel<<<521, 256, 0, stream>>>(adj, gpk, gpkT, W1, a1, W2, a2, consts,
                                            ipop, wih0, whh0, bih0, bhh0,
                                            wih1, whh1, bih1, bhh1, ip);
  gat_head_kernel<<<512, 256, 0, stream>>>(gpk, gpkT, feat, timei, Weight, Wv, consts, ip,
                                           mha_in_w, mha_in_b, mha_out_w, mha_out_b,
                                           fl1_w, fl1_b, fl2_w, fl2_b, fl3_w, fl3_b,
                                           (float*)d_out);
}